// Round 1
// baseline (2249.485 us; speedup 1.0000x reference)
//
#include <hip/hip_runtime.h>
#include <hip/hip_bf16.h>

// Problem constants
#define B_   8
#define L_   1024
#define C_   512
#define DI_  1024
#define K_   4
#define N_   16
#define R_   32
#define HW_  32
#define M_   (B_ * L_)   // 8192 rows

// Map scan position p -> spatial index l (same map for gather of u and scatter of y)
__device__ __forceinline__ int sp_map(int k, int p) {
  if (k == 0) return p;
  if (k == 1) return ((p & 31) << 5) | (p >> 5);      // (p%H)*W + p/H
  if (k == 2) return 1023 - p;
  int q = 1023 - p;
  return ((q & 31) << 5) | (q >> 5);
}

__device__ __forceinline__ float block_sum_256(float v, float* sm) {
  #pragma unroll
  for (int o = 32; o > 0; o >>= 1) v += __shfl_down(v, o);
  int wid = threadIdx.x >> 6;
  if ((threadIdx.x & 63) == 0) sm[wid] = v;
  __syncthreads();
  float r = sm[0] + sm[1] + sm[2] + sm[3];
  __syncthreads();
  return r;
}

// ---------------- 1) LayerNorm over C=512 ----------------
__global__ __launch_bounds__(256) void ln_kernel(const float* __restrict__ x,
    const float* __restrict__ w, const float* __restrict__ b, float* __restrict__ xn) {
  int row = blockIdx.x;
  const float* xr = x + (size_t)row * C_;
  int t = threadIdx.x;
  float v0 = xr[t], v1 = xr[t + 256];
  __shared__ float sm[4];
  float s = block_sum_256(v0 + v1, sm);
  float mu = s * (1.0f / C_);
  float d0 = v0 - mu, d1 = v1 - mu;
  float q = block_sum_256(d0 * d0 + d1 * d1, sm);
  float rs = rsqrtf(q * (1.0f / C_) + 1e-5f);
  float* xo = xn + (size_t)row * C_;
  xo[t]       = d0 * rs * w[t] + b[t];
  xo[t + 256] = d1 * rs * w[t + 256] + b[t + 256];
}

// ---------------- tiled f32 GEMM: C[m,n] = sum_k A[m,k]*Bw[n,k] ----------------
// mode 0: split columns [0,N/2) -> O0, [N/2,N) -> O1 (each row-stride N/2)
// mode 1: O0[m*N+n] = acc + resid[m*N+n]
__global__ __launch_bounds__(256) void gemm_nt(const float* __restrict__ A,
    const float* __restrict__ Bw, int M, int N, int K,
    float* __restrict__ O0, float* __restrict__ O1,
    const float* __restrict__ resid, int mode) {
  __shared__ float As[16][65];
  __shared__ float Bs[16][65];
  int bm = blockIdx.y * 64, bn = blockIdx.x * 64;
  int tid = threadIdx.x;
  int tr = tid >> 4, tc = tid & 15;
  float acc[4][4] = {};
  for (int k0 = 0; k0 < K; k0 += 16) {
    __syncthreads();
    #pragma unroll
    for (int i = 0; i < 4; ++i) {
      int r = (tid >> 4) + i * 16;
      int c = tid & 15;
      As[c][r] = A[(size_t)(bm + r) * K + k0 + c];
      Bs[c][r] = Bw[(size_t)(bn + r) * K + k0 + c];
    }
    __syncthreads();
    #pragma unroll
    for (int kk = 0; kk < 16; ++kk) {
      float av[4], bv[4];
      #pragma unroll
      for (int i = 0; i < 4; ++i) av[i] = As[kk][tr * 4 + i];
      #pragma unroll
      for (int j = 0; j < 4; ++j) bv[j] = Bs[kk][tc * 4 + j];
      #pragma unroll
      for (int i = 0; i < 4; ++i)
        #pragma unroll
        for (int j = 0; j < 4; ++j) acc[i][j] += av[i] * bv[j];
    }
  }
  #pragma unroll
  for (int i = 0; i < 4; ++i) {
    int m = bm + tr * 4 + i;
    #pragma unroll
    for (int j = 0; j < 4; ++j) {
      int n = bn + tc * 4 + j;
      float val = acc[i][j];
      if (mode == 0) {
        int half = N >> 1;
        if (n < half) O0[(size_t)m * half + n] = val;
        else          O1[(size_t)m * half + (n - half)] = val;
      } else {
        O0[(size_t)m * N + n] = val + resid[(size_t)m * N + n];
      }
    }
  }
}

// ---------------- 3) depthwise 3x3 conv + bias + SiLU ----------------
// xpart: (B*L, DI) viewed as (B,H,W,DI). out xc: (B*L, DI)
__global__ __launch_bounds__(256) void conv_silu_kernel(const float* __restrict__ xpart,
    const float* __restrict__ cw, const float* __restrict__ cb, float* __restrict__ xc) {
  int bl = blockIdx.x;
  int b = bl >> 10, l = bl & 1023;
  int h = l >> 5, w = l & 31;
  for (int d = threadIdx.x; d < DI_; d += 256) {
    float acc = cb[d];
    #pragma unroll
    for (int dy = -1; dy <= 1; ++dy) {
      int hh = h + dy;
      if (hh < 0 || hh >= HW_) continue;
      #pragma unroll
      for (int dx = -1; dx <= 1; ++dx) {
        int ww = w + dx;
        if (ww < 0 || ww >= HW_) continue;
        acc += cw[d * 9 + (dy + 1) * 3 + (dx + 1)] *
               xpart[((size_t)(b << 10) + (hh << 5) + ww) * DI_ + d];
      }
    }
    xc[(size_t)bl * DI_ + d] = acc / (1.0f + expf(-acc));
  }
}

// ---------------- 4) x_dbl[b,k,p,c] = sum_d xc[b, sp(k,p), d] * xproj[k,c,d] ----------------
// grid: B*K*64 blocks (16 p's each), 256 threads (4 waves; wave handles 4 p's, lane = c)
__global__ __launch_bounds__(256) void xdbl_kernel(const float* __restrict__ xc,
    const float* __restrict__ xproj, float* __restrict__ xdbl) {
  int blk = blockIdx.x;
  int pt = blk & 63;
  int k  = (blk >> 6) & 3;
  int b  = blk >> 8;
  int p0 = pt * 16;
  __shared__ float Xs[16][64];
  __shared__ float Ws[64][65];
  int lane = threadIdx.x & 63;
  int wv4 = (threadIdx.x >> 6) * 4;
  float acc[4] = {0.f, 0.f, 0.f, 0.f};
  for (int d0 = 0; d0 < DI_; d0 += 64) {
    __syncthreads();
    #pragma unroll
    for (int i = 0; i < 4; ++i) {
      int e = threadIdx.x + i * 256;
      int pi = e >> 6, col = e & 63;
      Xs[pi][col] = xc[((size_t)(b * 1024 + sp_map(k, p0 + pi))) * DI_ + d0 + col];
    }
    #pragma unroll
    for (int i = 0; i < 16; ++i) {
      int e = threadIdx.x + i * 256;
      int dd = e & 63, cc = e >> 6;
      Ws[dd][cc] = xproj[((size_t)(k * 64 + cc)) * DI_ + d0 + dd];
    }
    __syncthreads();
    #pragma unroll
    for (int dc = 0; dc < 64; ++dc) {
      float wval = Ws[dc][lane];
      #pragma unroll
      for (int q = 0; q < 4; ++q) acc[q] += wval * Xs[wv4 + q][dc];
    }
  }
  #pragma unroll
  for (int q = 0; q < 4; ++q) {
    int p = p0 + wv4 + q;
    xdbl[(((size_t)(b * 4 + k)) * 1024 + p) * 64 + lane] = acc[q];
  }
}

// ---------------- 5) selective scan ----------------
// grid: B*K*16 blocks, 64 threads. thread d = dch*64+lane, sequential over p.
__global__ __launch_bounds__(64) void scan_kernel(const float* __restrict__ xc,
    const float* __restrict__ xdbl, const float* __restrict__ dtw,
    const float* __restrict__ dtb, const float* __restrict__ Alogs,
    const float* __restrict__ Ds, __hip_bfloat16* __restrict__ ys) {
  int blk = blockIdx.x;
  int dch = blk & 15;
  int k   = (blk >> 4) & 3;
  int b   = blk >> 6;
  int d = dch * 64 + threadIdx.x;
  int kd = k * DI_ + d;

  float dtwr[32];
  #pragma unroll
  for (int r = 0; r < 32; ++r) dtwr[r] = dtw[(size_t)kd * 32 + r];
  float A[16], h[16];
  #pragma unroll
  for (int n = 0; n < 16; ++n) {
    A[n] = -expf(Alogs[(size_t)kd * 16 + n]);
    h[n] = 0.f;
  }
  float bias = dtb[kd];
  float Dv = Ds[kd];

  __shared__ float row[64];
  const float* xdbl_bk = xdbl + (size_t)(b * 4 + k) * 1024 * 64;

  for (int p = 0; p < 1024; ++p) {
    row[threadIdx.x] = xdbl_bk[p * 64 + threadIdx.x];
    __syncthreads();
    int sp = sp_map(k, p);
    float u = xc[((size_t)(b * 1024 + sp)) * DI_ + d];
    float dtr = bias;
    #pragma unroll
    for (int r = 0; r < 32; ++r) dtr += dtwr[r] * row[r];
    float dt = (dtr > 20.f) ? dtr : log1pf(expf(dtr));
    float dtu = dt * u;
    float y = 0.f;
    #pragma unroll
    for (int n = 0; n < 16; ++n) {
      h[n] = h[n] * expf(dt * A[n]) + dtu * row[32 + n];
      y += h[n] * row[48 + n];
    }
    y += Dv * u;
    ys[(((size_t)(b * 1024 + sp)) * 4 + k) * DI_ + d] = __float2bfloat16(y);
    __syncthreads();
  }
}

// ---------------- 6) merge(sum k) + LayerNorm(DI) + SiLU(z) gate ----------------
__global__ __launch_bounds__(256) void merge_kernel(const __hip_bfloat16* __restrict__ ys,
    const float* __restrict__ z, const float* __restrict__ ow, const float* __restrict__ ob,
    float* __restrict__ ym) {
  int bl = blockIdx.x;
  int t = threadIdx.x;
  float v[4];
  float s = 0.f;
  #pragma unroll
  for (int i = 0; i < 4; ++i) {
    int d = t + i * 256;
    float acc = 0.f;
    #pragma unroll
    for (int kk = 0; kk < 4; ++kk)
      acc += __bfloat162float(ys[(((size_t)bl) * 4 + kk) * DI_ + d]);
    v[i] = acc;
    s += acc;
  }
  __shared__ float sm[4];
  float tot = block_sum_256(s, sm);
  float mu = tot * (1.0f / DI_);
  float q = 0.f;
  #pragma unroll
  for (int i = 0; i < 4; ++i) { float dv = v[i] - mu; q += dv * dv; }
  float qs = block_sum_256(q, sm);
  float rs = rsqrtf(qs * (1.0f / DI_) + 1e-5f);
  #pragma unroll
  for (int i = 0; i < 4; ++i) {
    int d = t + i * 256;
    float ln = (v[i] - mu) * rs * ow[d] + ob[d];
    float zv = z[(size_t)bl * DI_ + d];
    ym[(size_t)bl * DI_ + d] = ln * (zv / (1.0f + expf(-zv)));
  }
}

// ---------------- launcher ----------------
extern "C" void kernel_launch(void* const* d_in, const int* in_sizes, int n_in,
                              void* d_out, int out_size, void* d_ws, size_t ws_size,
                              hipStream_t stream) {
  const float* x         = (const float*)d_in[0];
  const float* norm_w    = (const float*)d_in[1];
  const float* norm_b    = (const float*)d_in[2];
  const float* in_proj_w = (const float*)d_in[3];
  const float* conv_w    = (const float*)d_in[4];
  const float* conv_b    = (const float*)d_in[5];
  const float* x_proj_w  = (const float*)d_in[6];
  const float* dt_projs_w= (const float*)d_in[7];
  const float* dt_projs_b= (const float*)d_in[8];
  const float* A_logs    = (const float*)d_in[9];
  const float* Ds        = (const float*)d_in[10];
  const float* out_norm_w= (const float*)d_in[11];
  const float* out_norm_b= (const float*)d_in[12];
  const float* out_proj_w= (const float*)d_in[13];
  float* out = (float*)d_out;

  // workspace layout (bytes): total = 192,937,984 (~184 MiB)
  char* ws = (char*)d_ws;
  float* xn    = (float*)(ws);                                   // 16.78 MB
  float* xpart = (float*)(ws + 16777216ULL);                     // 33.55 MB
  float* z     = (float*)(ws + 50331648ULL);                     // 33.55 MB
  float* xc    = (float*)(ws + 83886080ULL);                     // 33.55 MB
  float* xdbl  = (float*)(ws + 117440512ULL);                    //  8.39 MB
  __hip_bfloat16* ys = (__hip_bfloat16*)(ws + 125829120ULL);     // 67.11 MB
  float* ym    = xpart;  // xpart is dead after conv; reuse for merged y

  // 1) LayerNorm
  ln_kernel<<<M_, 256, 0, stream>>>(x, norm_w, norm_b, xn);
  // 2) xz = xn @ in_proj_w.T  -> split xpart | z
  gemm_nt<<<dim3(2048 / 64, M_ / 64), 256, 0, stream>>>(
      xn, in_proj_w, M_, 2048, C_, xpart, z, nullptr, 0);
  // 3) depthwise conv + SiLU
  conv_silu_kernel<<<M_, 256, 0, stream>>>(xpart, conv_w, conv_b, xc);
  // 4) x_dbl projections (4 scan directions, permutation applied on load)
  xdbl_kernel<<<B_ * K_ * 64, 256, 0, stream>>>(xc, x_proj_w, xdbl);
  // 5) selective scan (writes ys at spatial index, bf16)
  scan_kernel<<<B_ * K_ * 16, 64, 0, stream>>>(
      xc, xdbl, dt_projs_w, dt_projs_b, A_logs, Ds, ys);
  // 6) merge + out-LN + SiLU(z) gate
  merge_kernel<<<M_, 256, 0, stream>>>(ys, z, out_norm_w, out_norm_b, ym);
  // 7) out = ym @ out_proj_w.T + resid
  gemm_nt<<<dim3(C_ / 64, M_ / 64), 256, 0, stream>>>(
      ym, out_proj_w, M_, C_, DI_, out, nullptr, x, 1);
}

// Round 2
// 1299.408 us; speedup vs baseline: 1.7312x; 1.7312x over previous
//
#include <hip/hip_runtime.h>
#include <hip/hip_bf16.h>

// Problem constants
#define B_   8
#define L_   1024
#define C_   512
#define DI_  1024
#define K_   4
#define N_   16
#define R_   32
#define HW_  32
#define M_   (B_ * L_)   // 8192 rows
#define NC_  8           // scan chunks
#define CL_  128         // chunk length = L_/NC_

// Map scan position p -> spatial index l (same map for gather of u and scatter of y)
__device__ __forceinline__ int sp_map(int k, int p) {
  if (k == 0) return p;
  if (k == 1) return ((p & 31) << 5) | (p >> 5);      // (p%H)*W + p/H
  if (k == 2) return 1023 - p;
  int q = 1023 - p;
  return ((q & 31) << 5) | (q >> 5);
}

__device__ __forceinline__ float block_sum_256(float v, float* sm) {
  #pragma unroll
  for (int o = 32; o > 0; o >>= 1) v += __shfl_down(v, o);
  int wid = threadIdx.x >> 6;
  if ((threadIdx.x & 63) == 0) sm[wid] = v;
  __syncthreads();
  float r = sm[0] + sm[1] + sm[2] + sm[3];
  __syncthreads();
  return r;
}

// ---------------- 1) LayerNorm over C=512 ----------------
__global__ __launch_bounds__(256) void ln_kernel(const float* __restrict__ x,
    const float* __restrict__ w, const float* __restrict__ b, float* __restrict__ xn) {
  int row = blockIdx.x;
  const float* xr = x + (size_t)row * C_;
  int t = threadIdx.x;
  float v0 = xr[t], v1 = xr[t + 256];
  __shared__ float sm[4];
  float s = block_sum_256(v0 + v1, sm);
  float mu = s * (1.0f / C_);
  float d0 = v0 - mu, d1 = v1 - mu;
  float q = block_sum_256(d0 * d0 + d1 * d1, sm);
  float rs = rsqrtf(q * (1.0f / C_) + 1e-5f);
  float* xo = xn + (size_t)row * C_;
  xo[t]       = d0 * rs * w[t] + b[t];
  xo[t + 256] = d1 * rs * w[t + 256] + b[t + 256];
}

// ---------------- tiled f32 GEMM: C[m,n] = sum_k A[m,k]*Bw[n,k] ----------------
__global__ __launch_bounds__(256) void gemm_nt(const float* __restrict__ A,
    const float* __restrict__ Bw, int M, int N, int K,
    float* __restrict__ O0, float* __restrict__ O1,
    const float* __restrict__ resid, int mode) {
  __shared__ float As[16][65];
  __shared__ float Bs[16][65];
  int bm = blockIdx.y * 64, bn = blockIdx.x * 64;
  int tid = threadIdx.x;
  int tr = tid >> 4, tc = tid & 15;
  float acc[4][4] = {};
  for (int k0 = 0; k0 < K; k0 += 16) {
    __syncthreads();
    #pragma unroll
    for (int i = 0; i < 4; ++i) {
      int r = (tid >> 4) + i * 16;
      int c = tid & 15;
      As[c][r] = A[(size_t)(bm + r) * K + k0 + c];
      Bs[c][r] = Bw[(size_t)(bn + r) * K + k0 + c];
    }
    __syncthreads();
    #pragma unroll
    for (int kk = 0; kk < 16; ++kk) {
      float av[4], bv[4];
      #pragma unroll
      for (int i = 0; i < 4; ++i) av[i] = As[kk][tr * 4 + i];
      #pragma unroll
      for (int j = 0; j < 4; ++j) bv[j] = Bs[kk][tc * 4 + j];
      #pragma unroll
      for (int i = 0; i < 4; ++i)
        #pragma unroll
        for (int j = 0; j < 4; ++j) acc[i][j] += av[i] * bv[j];
    }
  }
  #pragma unroll
  for (int i = 0; i < 4; ++i) {
    int m = bm + tr * 4 + i;
    #pragma unroll
    for (int j = 0; j < 4; ++j) {
      int n = bn + tc * 4 + j;
      float val = acc[i][j];
      if (mode == 0) {
        int half = N >> 1;
        if (n < half) O0[(size_t)m * half + n] = val;
        else          O1[(size_t)m * half + (n - half)] = val;
      } else {
        O0[(size_t)m * N + n] = val + resid[(size_t)m * N + n];
      }
    }
  }
}

// ---------------- 3) depthwise 3x3 conv + bias + SiLU ----------------
__global__ __launch_bounds__(256) void conv_silu_kernel(const float* __restrict__ xpart,
    const float* __restrict__ cw, const float* __restrict__ cb, float* __restrict__ xc) {
  int bl = blockIdx.x;
  int b = bl >> 10, l = bl & 1023;
  int h = l >> 5, w = l & 31;
  for (int d = threadIdx.x; d < DI_; d += 256) {
    float acc = cb[d];
    #pragma unroll
    for (int dy = -1; dy <= 1; ++dy) {
      int hh = h + dy;
      if (hh < 0 || hh >= HW_) continue;
      #pragma unroll
      for (int dx = -1; dx <= 1; ++dx) {
        int ww = w + dx;
        if (ww < 0 || ww >= HW_) continue;
        acc += cw[d * 9 + (dy + 1) * 3 + (dx + 1)] *
               xpart[((size_t)(b << 10) + (hh << 5) + ww) * DI_ + d];
      }
    }
    xc[(size_t)bl * DI_ + d] = acc / (1.0f + expf(-acc));
  }
}

// ---------------- 4) x_dbl[b,k,p,c] = sum_d xc[b, sp(k,p), d] * xproj[k,c,d] ----------------
__global__ __launch_bounds__(256) void xdbl_kernel(const float* __restrict__ xc,
    const float* __restrict__ xproj, float* __restrict__ xdbl) {
  int blk = blockIdx.x;
  int pt = blk & 63;
  int k  = (blk >> 6) & 3;
  int b  = blk >> 8;
  int p0 = pt * 16;
  __shared__ float Xs[16][64];
  __shared__ float Ws[64][65];
  int lane = threadIdx.x & 63;
  int wv4 = (threadIdx.x >> 6) * 4;
  float acc[4] = {0.f, 0.f, 0.f, 0.f};
  for (int d0 = 0; d0 < DI_; d0 += 64) {
    __syncthreads();
    #pragma unroll
    for (int i = 0; i < 4; ++i) {
      int e = threadIdx.x + i * 256;
      int pi = e >> 6, col = e & 63;
      Xs[pi][col] = xc[((size_t)(b * 1024 + sp_map(k, p0 + pi))) * DI_ + d0 + col];
    }
    #pragma unroll
    for (int i = 0; i < 16; ++i) {
      int e = threadIdx.x + i * 256;
      int dd = e & 63, cc = e >> 6;
      Ws[dd][cc] = xproj[((size_t)(k * 64 + cc)) * DI_ + d0 + dd];
    }
    __syncthreads();
    #pragma unroll
    for (int dc = 0; dc < 64; ++dc) {
      float wval = Ws[dc][lane];
      #pragma unroll
      for (int q = 0; q < 4; ++q) acc[q] += wval * Xs[wv4 + q][dc];
    }
  }
  #pragma unroll
  for (int q = 0; q < 4; ++q) {
    int p = p0 + wv4 + q;
    xdbl[(((size_t)(b * 4 + k)) * 1024 + p) * 64 + lane] = acc[q];
  }
}

// ---------------- 5a) scan pass A: per-chunk local scan + chunk summary ----------------
// blk = (((b*4+k)*16+dch)*NC_+c); 64 threads, thread = lane -> d = dch*64+lane
// stores: st[blk*2048 + n*64 + lane]        = P[n]  (cumulative a-product over chunk)
//         st[blk*2048 + 1024 + n*64 + lane] = h_end_local[n]
__global__ __launch_bounds__(64) void scan_passA(const float* __restrict__ xc,
    const float* __restrict__ xdbl, const float* __restrict__ dtw,
    const float* __restrict__ dtb, const float* __restrict__ Alogs,
    float* __restrict__ st) {
  int blk = blockIdx.x;
  int c   = blk & (NC_ - 1);
  int dch = (blk >> 3) & 15;
  int k   = (blk >> 7) & 3;
  int b   = blk >> 9;
  int lane = threadIdx.x;
  int d = dch * 64 + lane;
  int kd = k * DI_ + d;

  float dtwr[32];
  #pragma unroll
  for (int r = 0; r < 32; ++r) dtwr[r] = dtw[(size_t)kd * 32 + r];
  float A[16], h[16];
  #pragma unroll
  for (int n = 0; n < 16; ++n) { A[n] = -__expf(Alogs[(size_t)kd * 16 + n]); h[n] = 0.f; }
  float bias = dtb[kd];
  float S = 0.f;

  __shared__ float row[64];
  const float* xdbl_bk = xdbl + (size_t)(b * 4 + k) * 1024 * 64;
  int p0 = c * CL_;
  for (int p = p0; p < p0 + CL_; ++p) {
    __syncthreads();
    row[lane] = xdbl_bk[p * 64 + lane];
    __syncthreads();
    int sp = sp_map(k, p);
    float u = xc[((size_t)(b * 1024 + sp)) * DI_ + d];
    float dtr = bias;
    #pragma unroll
    for (int r = 0; r < 32; ++r) dtr += dtwr[r] * row[r];
    float dt = (dtr > 20.f) ? dtr : log1pf(__expf(dtr));
    S += dt;
    float dtu = dt * u;
    #pragma unroll
    for (int n = 0; n < 16; ++n)
      h[n] = h[n] * __expf(dt * A[n]) + dtu * row[32 + n];
  }
  size_t base = (size_t)blk * 2048;
  #pragma unroll
  for (int n = 0; n < 16; ++n) {
    st[base + n * 64 + lane]        = __expf(A[n] * S);  // prod of exp(dt*A) = exp(A*sum dt)
    st[base + 1024 + n * 64 + lane] = h[n];
  }
}

// ---------------- 5b) combine chunk states; overwrite h-slot with H_in(c) ----------------
__global__ __launch_bounds__(256) void scan_mid(float* __restrict__ st) {
  int idx = blockIdx.x * 256 + threadIdx.x;   // 32768 threads: (g, lane)
  int lane = idx & 63;
  int g = idx >> 6;                           // (b*4+k)*16+dch
  float H[16];
  #pragma unroll
  for (int n = 0; n < 16; ++n) H[n] = 0.f;
  for (int c = 0; c < NC_; ++c) {
    size_t base = ((size_t)g * NC_ + c) * 2048;
    #pragma unroll
    for (int n = 0; n < 16; ++n) {
      float P  = st[base + n * 64 + lane];
      float he = st[base + 1024 + n * 64 + lane];
      st[base + 1024 + n * 64 + lane] = H[n];           // H_in for chunk c
      H[n] = he + P * H[n];
    }
  }
}

// ---------------- 5c) scan pass B: rescan chunk from H_in, emit y ----------------
__global__ __launch_bounds__(64) void scan_passB(const float* __restrict__ xc,
    const float* __restrict__ xdbl, const float* __restrict__ dtw,
    const float* __restrict__ dtb, const float* __restrict__ Alogs,
    const float* __restrict__ Ds, const float* __restrict__ st,
    __hip_bfloat16* __restrict__ ys) {
  int blk = blockIdx.x;
  int c   = blk & (NC_ - 1);
  int dch = (blk >> 3) & 15;
  int k   = (blk >> 7) & 3;
  int b   = blk >> 9;
  int lane = threadIdx.x;
  int d = dch * 64 + lane;
  int kd = k * DI_ + d;

  float dtwr[32];
  #pragma unroll
  for (int r = 0; r < 32; ++r) dtwr[r] = dtw[(size_t)kd * 32 + r];
  float A[16], h[16];
  size_t base = (size_t)blk * 2048;
  #pragma unroll
  for (int n = 0; n < 16; ++n) {
    A[n] = -__expf(Alogs[(size_t)kd * 16 + n]);
    h[n] = st[base + 1024 + n * 64 + lane];
  }
  float bias = dtb[kd];
  float Dv = Ds[kd];

  __shared__ float row[64];
  const float* xdbl_bk = xdbl + (size_t)(b * 4 + k) * 1024 * 64;
  int p0 = c * CL_;
  for (int p = p0; p < p0 + CL_; ++p) {
    __syncthreads();
    row[lane] = xdbl_bk[p * 64 + lane];
    __syncthreads();
    int sp = sp_map(k, p);
    float u = xc[((size_t)(b * 1024 + sp)) * DI_ + d];
    float dtr = bias;
    #pragma unroll
    for (int r = 0; r < 32; ++r) dtr += dtwr[r] * row[r];
    float dt = (dtr > 20.f) ? dtr : log1pf(__expf(dtr));
    float dtu = dt * u;
    float y = 0.f;
    #pragma unroll
    for (int n = 0; n < 16; ++n) {
      h[n] = h[n] * __expf(dt * A[n]) + dtu * row[32 + n];
      y += h[n] * row[48 + n];
    }
    y += Dv * u;
    ys[(((size_t)(b * 1024 + sp)) * 4 + k) * DI_ + d] = __float2bfloat16(y);
  }
}

// ---------------- 6) merge(sum k) + LayerNorm(DI) + SiLU(z) gate ----------------
__global__ __launch_bounds__(256) void merge_kernel(const __hip_bfloat16* __restrict__ ys,
    const float* __restrict__ z, const float* __restrict__ ow, const float* __restrict__ ob,
    float* __restrict__ ym) {
  int bl = blockIdx.x;
  int t = threadIdx.x;
  float v[4];
  float s = 0.f;
  #pragma unroll
  for (int i = 0; i < 4; ++i) {
    int d = t + i * 256;
    float acc = 0.f;
    #pragma unroll
    for (int kk = 0; kk < 4; ++kk)
      acc += __bfloat162float(ys[(((size_t)bl) * 4 + kk) * DI_ + d]);
    v[i] = acc;
    s += acc;
  }
  __shared__ float sm[4];
  float tot = block_sum_256(s, sm);
  float mu = tot * (1.0f / DI_);
  float q = 0.f;
  #pragma unroll
  for (int i = 0; i < 4; ++i) { float dv = v[i] - mu; q += dv * dv; }
  float qs = block_sum_256(q, sm);
  float rs = rsqrtf(qs * (1.0f / DI_) + 1e-5f);
  #pragma unroll
  for (int i = 0; i < 4; ++i) {
    int d = t + i * 256;
    float ln = (v[i] - mu) * rs * ow[d] + ob[d];
    float zv = z[(size_t)bl * DI_ + d];
    ym[(size_t)bl * DI_ + d] = ln * (zv / (1.0f + expf(-zv)));
  }
}

// ---------------- launcher ----------------
extern "C" void kernel_launch(void* const* d_in, const int* in_sizes, int n_in,
                              void* d_out, int out_size, void* d_ws, size_t ws_size,
                              hipStream_t stream) {
  const float* x         = (const float*)d_in[0];
  const float* norm_w    = (const float*)d_in[1];
  const float* norm_b    = (const float*)d_in[2];
  const float* in_proj_w = (const float*)d_in[3];
  const float* conv_w    = (const float*)d_in[4];
  const float* conv_b    = (const float*)d_in[5];
  const float* x_proj_w  = (const float*)d_in[6];
  const float* dt_projs_w= (const float*)d_in[7];
  const float* dt_projs_b= (const float*)d_in[8];
  const float* A_logs    = (const float*)d_in[9];
  const float* Ds        = (const float*)d_in[10];
  const float* out_norm_w= (const float*)d_in[11];
  const float* out_norm_b= (const float*)d_in[12];
  const float* out_proj_w= (const float*)d_in[13];
  float* out = (float*)d_out;

  // workspace layout (bytes): total = 192,937,984 (~184 MiB)
  char* ws = (char*)d_ws;
  float* xn    = (float*)(ws);                                   // 16.78 MB
  float* xpart = (float*)(ws + 16777216ULL);                     // 33.55 MB
  float* z     = (float*)(ws + 50331648ULL);                     // 33.55 MB
  float* xc    = (float*)(ws + 83886080ULL);                     // 33.55 MB
  float* xdbl  = (float*)(ws + 117440512ULL);                    //  8.39 MB
  __hip_bfloat16* ys = (__hip_bfloat16*)(ws + 125829120ULL);     // 67.11 MB
  float* st    = xpart;  // chunk-state buffer (33.55 MB) reuses dead xpart region
  float* ym    = xpart;  // merged y reuses it again after scan

  // 1) LayerNorm
  ln_kernel<<<M_, 256, 0, stream>>>(x, norm_w, norm_b, xn);
  // 2) xz = xn @ in_proj_w.T  -> split xpart | z
  gemm_nt<<<dim3(2048 / 64, M_ / 64), 256, 0, stream>>>(
      xn, in_proj_w, M_, 2048, C_, xpart, z, nullptr, 0);
  // 3) depthwise conv + SiLU
  conv_silu_kernel<<<M_, 256, 0, stream>>>(xpart, conv_w, conv_b, xc);
  // 4) x_dbl projections (4 scan directions, permutation applied on load)
  xdbl_kernel<<<B_ * K_ * 64, 256, 0, stream>>>(xc, x_proj_w, xdbl);
  // 5) chunked parallel selective scan
  scan_passA<<<B_ * K_ * 16 * NC_, 64, 0, stream>>>(
      xc, xdbl, dt_projs_w, dt_projs_b, A_logs, st);
  scan_mid<<<(B_ * K_ * DI_) / 256, 256, 0, stream>>>(st);
  scan_passB<<<B_ * K_ * 16 * NC_, 64, 0, stream>>>(
      xc, xdbl, dt_projs_w, dt_projs_b, A_logs, Ds, st, ys);
  // 6) merge + out-LN + SiLU(z) gate
  merge_kernel<<<M_, 256, 0, stream>>>(ys, z, out_norm_w, out_norm_b, ym);
  // 7) out = ym @ out_proj_w.T + resid
  gemm_nt<<<dim3(C_ / 64, M_ / 64), 256, 0, stream>>>(
      ym, out_proj_w, M_, C_, DI_, out, nullptr, x, 1);
}

// Round 3
// 861.014 us; speedup vs baseline: 2.6126x; 1.5092x over previous
//
#include <hip/hip_runtime.h>
#include <hip/hip_bf16.h>

// Problem constants
#define B_   8
#define L_   1024
#define C_   512
#define DI_  1024
#define K_   4
#define N_   16
#define R_   32
#define HW_  32
#define M_   (B_ * L_)   // 8192 rows
#define NC_  8           // scan chunks
#define CL_  128         // chunk length = L_/NC_

typedef __attribute__((ext_vector_type(8))) short short8;   // 8 bf16 (4 VGPRs)
typedef __attribute__((ext_vector_type(4))) float f32x4;

__device__ __forceinline__ void gload_lds16(const void* g, void* l) {
  __builtin_amdgcn_global_load_lds(
      (const __attribute__((address_space(1))) void*)g,
      (__attribute__((address_space(3))) void*)l, 16, 0, 0);
}

// Map scan position p -> spatial index l (same map for gather of u and scatter of y)
__device__ __forceinline__ int sp_map(int k, int p) {
  if (k == 0) return p;
  if (k == 1) return ((p & 31) << 5) | (p >> 5);      // (p%H)*W + p/H
  if (k == 2) return 1023 - p;
  int q = 1023 - p;
  return ((q & 31) << 5) | (q >> 5);
}

__device__ __forceinline__ float block_sum_256(float v, float* sm) {
  #pragma unroll
  for (int o = 32; o > 0; o >>= 1) v += __shfl_down(v, o);
  int wid = threadIdx.x >> 6;
  if ((threadIdx.x & 63) == 0) sm[wid] = v;
  __syncthreads();
  float r = sm[0] + sm[1] + sm[2] + sm[3];
  __syncthreads();
  return r;
}

// ---------------- weight cast f32 -> bf16 (vectorized) ----------------
__global__ __launch_bounds__(256) void cast_bf16_kernel(const float* __restrict__ in,
    __hip_bfloat16* __restrict__ out, int n4) {
  int i = blockIdx.x * 256 + threadIdx.x;
  if (i >= n4) return;
  float4 v = ((const float4*)in)[i];
  union { __hip_bfloat16 h[4]; short4 s; } pk;
  pk.h[0] = __float2bfloat16(v.x); pk.h[1] = __float2bfloat16(v.y);
  pk.h[2] = __float2bfloat16(v.z); pk.h[3] = __float2bfloat16(v.w);
  ((short4*)out)[i] = pk.s;
}

// ---------------- 1) LayerNorm over C=512 (emits bf16) ----------------
__global__ __launch_bounds__(256) void ln_kernel(const float* __restrict__ x,
    const float* __restrict__ w, const float* __restrict__ b,
    __hip_bfloat16* __restrict__ xn) {
  int row = blockIdx.x;
  const float* xr = x + (size_t)row * C_;
  int t = threadIdx.x;
  float v0 = xr[t], v1 = xr[t + 256];
  __shared__ float sm[4];
  float s = block_sum_256(v0 + v1, sm);
  float mu = s * (1.0f / C_);
  float d0 = v0 - mu, d1 = v1 - mu;
  float q = block_sum_256(d0 * d0 + d1 * d1, sm);
  float rs = rsqrtf(q * (1.0f / C_) + 1e-5f);
  __hip_bfloat16* xo = xn + (size_t)row * C_;
  xo[t]       = __float2bfloat16(d0 * rs * w[t] + b[t]);
  xo[t + 256] = __float2bfloat16(d1 * rs * w[t + 256] + b[t + 256]);
}

// ---------------- bf16 MFMA GEMM: C[m,n] = sum_k A[m,k]*Bw[n,k] ----------------
// m97 structure: 128x128 tile, BK=32, 4 waves (2x2), 4x4 16x16x32 fragments/wave.
// MODE 0: split cols [0,N/2)->O0, [N/2,N)->O1 (row stride N/2), f32 out.
// MODE 1: O0[m*N+n] = acc + resid[m*N+n].
template <int MODE>
__global__ __launch_bounds__(256) void gemm_bf16(
    const __hip_bfloat16* __restrict__ A, const __hip_bfloat16* __restrict__ Bw,
    const int M, const int N, const int K,
    float* __restrict__ O0, float* __restrict__ O1, const float* __restrict__ resid) {
  __shared__ __align__(16) __hip_bfloat16 Asm[128][32];  // 8 KB, linear (global_load_lds dest)
  __shared__ __align__(16) __hip_bfloat16 Bsm[128][32];  // 8 KB
  const int bm = blockIdx.y * 128, bn = blockIdx.x * 128;
  const int tid = threadIdx.x, lane = tid & 63, wid = tid >> 6;
  const int wr = (wid >> 1) * 64, wc = (wid & 1) * 64;   // wave's 64x64 output origin
  const int fr = lane & 15, fq = lane >> 4;

  f32x4 acc[4][4] = {};

  // staging geometry: 512 16B-chunks per tile; chunk q -> row q>>2, col (q&3)*8 elems
  const int r0 = tid >> 2, c0 = (tid & 3) * 8;
  const int r1 = (tid + 256) >> 2;
  const __hip_bfloat16* Ag0 = A + (size_t)(bm + r0) * K + c0;
  const __hip_bfloat16* Ag1 = A + (size_t)(bm + r1) * K + c0;
  const __hip_bfloat16* Bg0 = Bw + (size_t)(bn + r0) * K + c0;
  const __hip_bfloat16* Bg1 = Bw + (size_t)(bn + r1) * K + c0;
  char* ldsA0 = (char*)Asm + wid * 1024;          // wave-uniform base; HW adds lane*16
  char* ldsA1 = (char*)Asm + 4096 + wid * 1024;
  char* ldsB0 = (char*)Bsm + wid * 1024;
  char* ldsB1 = (char*)Bsm + 4096 + wid * 1024;

  for (int k0 = 0; k0 < K; k0 += 32) {
    __syncthreads();                 // previous iter's reads done before overwrite
    gload_lds16(Ag0 + k0, ldsA0);
    gload_lds16(Ag1 + k0, ldsA1);
    gload_lds16(Bg0 + k0, ldsB0);
    gload_lds16(Bg1 + k0, ldsB1);
    __syncthreads();                 // compiler drains vmcnt before barrier

    short8 af[4], bf[4];
    #pragma unroll
    for (int i = 0; i < 4; ++i) {
      af[i] = *(const short8*)((const char*)Asm + (wr + i * 16 + fr) * 64 + fq * 16);
      bf[i] = *(const short8*)((const char*)Bsm + (wc + i * 16 + fr) * 64 + fq * 16);
    }
    #pragma unroll
    for (int i = 0; i < 4; ++i)
      #pragma unroll
      for (int j = 0; j < 4; ++j)
        acc[i][j] = __builtin_amdgcn_mfma_f32_16x16x32_bf16(af[i], bf[j], acc[i][j], 0, 0, 0);
  }

  // C/D layout (16x16x32): col = lane&15, row = (lane>>4)*4 + reg
  const int half = N >> 1;
  #pragma unroll
  for (int i = 0; i < 4; ++i) {
    const int mrow = bm + wr + i * 16 + fq * 4;
    #pragma unroll
    for (int j = 0; j < 4; ++j) {
      const int n = bn + wc + j * 16 + fr;
      #pragma unroll
      for (int r = 0; r < 4; ++r) {
        const int m = mrow + r;
        const float v = acc[i][j][r];
        if (MODE == 0) {
          if (n < half) O0[(size_t)m * half + n] = v;
          else          O1[(size_t)m * half + (n - half)] = v;
        } else {
          O0[(size_t)m * N + n] = v + resid[(size_t)m * N + n];
        }
      }
    }
  }
}

// ---------------- 3) depthwise 3x3 conv + bias + SiLU ----------------
__global__ __launch_bounds__(256) void conv_silu_kernel(const float* __restrict__ xpart,
    const float* __restrict__ cw, const float* __restrict__ cb, float* __restrict__ xc) {
  int bl = blockIdx.x;
  int b = bl >> 10, l = bl & 1023;
  int h = l >> 5, w = l & 31;
  for (int d = threadIdx.x; d < DI_; d += 256) {
    float acc = cb[d];
    #pragma unroll
    for (int dy = -1; dy <= 1; ++dy) {
      int hh = h + dy;
      if (hh < 0 || hh >= HW_) continue;
      #pragma unroll
      for (int dx = -1; dx <= 1; ++dx) {
        int ww = w + dx;
        if (ww < 0 || ww >= HW_) continue;
        acc += cw[d * 9 + (dy + 1) * 3 + (dx + 1)] *
               xpart[((size_t)(b << 10) + (hh << 5) + ww) * DI_ + d];
      }
    }
    xc[(size_t)bl * DI_ + d] = acc / (1.0f + expf(-acc));
  }
}

// ---------------- 4) x_dbl[b,k,p,c] = sum_d xc[b, sp(k,p), d] * xproj[k,c,d] ----------------
__global__ __launch_bounds__(256) void xdbl_kernel(const float* __restrict__ xc,
    const float* __restrict__ xproj, float* __restrict__ xdbl) {
  int blk = blockIdx.x;
  int pt = blk & 63;
  int k  = (blk >> 6) & 3;
  int b  = blk >> 8;
  int p0 = pt * 16;
  __shared__ float Xs[16][64];
  __shared__ float Ws[64][65];
  int lane = threadIdx.x & 63;
  int wv4 = (threadIdx.x >> 6) * 4;
  float acc[4] = {0.f, 0.f, 0.f, 0.f};
  for (int d0 = 0; d0 < DI_; d0 += 64) {
    __syncthreads();
    #pragma unroll
    for (int i = 0; i < 4; ++i) {
      int e = threadIdx.x + i * 256;
      int pi = e >> 6, col = e & 63;
      Xs[pi][col] = xc[((size_t)(b * 1024 + sp_map(k, p0 + pi))) * DI_ + d0 + col];
    }
    #pragma unroll
    for (int i = 0; i < 16; ++i) {
      int e = threadIdx.x + i * 256;
      int dd = e & 63, cc = e >> 6;
      Ws[dd][cc] = xproj[((size_t)(k * 64 + cc)) * DI_ + d0 + dd];
    }
    __syncthreads();
    #pragma unroll
    for (int dc = 0; dc < 64; ++dc) {
      float wval = Ws[dc][lane];
      #pragma unroll
      for (int q = 0; q < 4; ++q) acc[q] += wval * Xs[wv4 + q][dc];
    }
  }
  #pragma unroll
  for (int q = 0; q < 4; ++q) {
    int p = p0 + wv4 + q;
    xdbl[(((size_t)(b * 4 + k)) * 1024 + p) * 64 + lane] = acc[q];
  }
}

// ---------------- 5a) scan pass A: per-chunk local scan + chunk summary ----------------
__global__ __launch_bounds__(64) void scan_passA(const float* __restrict__ xc,
    const float* __restrict__ xdbl, const float* __restrict__ dtw,
    const float* __restrict__ dtb, const float* __restrict__ Alogs,
    float* __restrict__ st) {
  int blk = blockIdx.x;
  int c   = blk & (NC_ - 1);
  int dch = (blk >> 3) & 15;
  int k   = (blk >> 7) & 3;
  int b   = blk >> 9;
  int lane = threadIdx.x;
  int d = dch * 64 + lane;
  int kd = k * DI_ + d;

  float dtwr[32];
  #pragma unroll
  for (int r = 0; r < 32; ++r) dtwr[r] = dtw[(size_t)kd * 32 + r];
  float A[16], h[16];
  #pragma unroll
  for (int n = 0; n < 16; ++n) { A[n] = -__expf(Alogs[(size_t)kd * 16 + n]); h[n] = 0.f; }
  float bias = dtb[kd];
  float S = 0.f;

  __shared__ float row[64];
  const float* xdbl_bk = xdbl + (size_t)(b * 4 + k) * 1024 * 64;
  int p0 = c * CL_;
  for (int p = p0; p < p0 + CL_; ++p) {
    __syncthreads();
    row[lane] = xdbl_bk[p * 64 + lane];
    __syncthreads();
    int sp = sp_map(k, p);
    float u = xc[((size_t)(b * 1024 + sp)) * DI_ + d];
    float dtr = bias;
    #pragma unroll
    for (int r = 0; r < 32; ++r) dtr += dtwr[r] * row[r];
    float dt = (dtr > 20.f) ? dtr : log1pf(__expf(dtr));
    S += dt;
    float dtu = dt * u;
    #pragma unroll
    for (int n = 0; n < 16; ++n)
      h[n] = h[n] * __expf(dt * A[n]) + dtu * row[32 + n];
  }
  size_t base = (size_t)blk * 2048;
  #pragma unroll
  for (int n = 0; n < 16; ++n) {
    st[base + n * 64 + lane]        = __expf(A[n] * S);  // prod exp(dt*A) = exp(A*S)
    st[base + 1024 + n * 64 + lane] = h[n];
  }
}

// ---------------- 5b) combine chunk states; overwrite h-slot with H_in(c) ----------------
__global__ __launch_bounds__(256) void scan_mid(float* __restrict__ st) {
  int idx = blockIdx.x * 256 + threadIdx.x;   // 32768 threads: (g, lane)
  int lane = idx & 63;
  int g = idx >> 6;                           // (b*4+k)*16+dch
  float H[16];
  #pragma unroll
  for (int n = 0; n < 16; ++n) H[n] = 0.f;
  for (int c = 0; c < NC_; ++c) {
    size_t base = ((size_t)g * NC_ + c) * 2048;
    #pragma unroll
    for (int n = 0; n < 16; ++n) {
      float P  = st[base + n * 64 + lane];
      float he = st[base + 1024 + n * 64 + lane];
      st[base + 1024 + n * 64 + lane] = H[n];           // H_in for chunk c
      H[n] = he + P * H[n];
    }
  }
}

// ---------------- 5c) scan pass B: rescan chunk from H_in, emit y ----------------
__global__ __launch_bounds__(64) void scan_passB(const float* __restrict__ xc,
    const float* __restrict__ xdbl, const float* __restrict__ dtw,
    const float* __restrict__ dtb, const float* __restrict__ Alogs,
    const float* __restrict__ Ds, const float* __restrict__ st,
    __hip_bfloat16* __restrict__ ys) {
  int blk = blockIdx.x;
  int c   = blk & (NC_ - 1);
  int dch = (blk >> 3) & 15;
  int k   = (blk >> 7) & 3;
  int b   = blk >> 9;
  int lane = threadIdx.x;
  int d = dch * 64 + lane;
  int kd = k * DI_ + d;

  float dtwr[32];
  #pragma unroll
  for (int r = 0; r < 32; ++r) dtwr[r] = dtw[(size_t)kd * 32 + r];
  float A[16], h[16];
  size_t base = (size_t)blk * 2048;
  #pragma unroll
  for (int n = 0; n < 16; ++n) {
    A[n] = -__expf(Alogs[(size_t)kd * 16 + n]);
    h[n] = st[base + 1024 + n * 64 + lane];
  }
  float bias = dtb[kd];
  float Dv = Ds[kd];

  __shared__ float row[64];
  const float* xdbl_bk = xdbl + (size_t)(b * 4 + k) * 1024 * 64;
  int p0 = c * CL_;
  for (int p = p0; p < p0 + CL_; ++p) {
    __syncthreads();
    row[lane] = xdbl_bk[p * 64 + lane];
    __syncthreads();
    int sp = sp_map(k, p);
    float u = xc[((size_t)(b * 1024 + sp)) * DI_ + d];
    float dtr = bias;
    #pragma unroll
    for (int r = 0; r < 32; ++r) dtr += dtwr[r] * row[r];
    float dt = (dtr > 20.f) ? dtr : log1pf(__expf(dtr));
    float dtu = dt * u;
    float y = 0.f;
    #pragma unroll
    for (int n = 0; n < 16; ++n) {
      h[n] = h[n] * __expf(dt * A[n]) + dtu * row[32 + n];
      y += h[n] * row[48 + n];
    }
    y += Dv * u;
    ys[(((size_t)(b * 1024 + sp)) * 4 + k) * DI_ + d] = __float2bfloat16(y);
  }
}

// ---------------- 6) merge(sum k) + LayerNorm(DI) + SiLU(z) gate (emits bf16) ----------------
__global__ __launch_bounds__(256) void merge_kernel(const __hip_bfloat16* __restrict__ ys,
    const float* __restrict__ z, const float* __restrict__ ow, const float* __restrict__ ob,
    __hip_bfloat16* __restrict__ ym) {
  int bl = blockIdx.x;
  int t = threadIdx.x;
  float v[4];
  float s = 0.f;
  #pragma unroll
  for (int i = 0; i < 4; ++i) {
    int d = t + i * 256;
    float acc = 0.f;
    #pragma unroll
    for (int kk = 0; kk < 4; ++kk)
      acc += __bfloat162float(ys[(((size_t)bl) * 4 + kk) * DI_ + d]);
    v[i] = acc;
    s += acc;
  }
  __shared__ float sm[4];
  float tot = block_sum_256(s, sm);
  float mu = tot * (1.0f / DI_);
  float q = 0.f;
  #pragma unroll
  for (int i = 0; i < 4; ++i) { float dv = v[i] - mu; q += dv * dv; }
  float qs = block_sum_256(q, sm);
  float rs = rsqrtf(qs * (1.0f / DI_) + 1e-5f);
  #pragma unroll
  for (int i = 0; i < 4; ++i) {
    int d = t + i * 256;
    float ln = (v[i] - mu) * rs * ow[d] + ob[d];
    float zv = z[(size_t)bl * DI_ + d];
    ym[(size_t)bl * DI_ + d] = __float2bfloat16(ln * (zv / (1.0f + expf(-zv))));
  }
}

// ---------------- launcher ----------------
extern "C" void kernel_launch(void* const* d_in, const int* in_sizes, int n_in,
                              void* d_out, int out_size, void* d_ws, size_t ws_size,
                              hipStream_t stream) {
  const float* x         = (const float*)d_in[0];
  const float* norm_w    = (const float*)d_in[1];
  const float* norm_b    = (const float*)d_in[2];
  const float* in_proj_w = (const float*)d_in[3];
  const float* conv_w    = (const float*)d_in[4];
  const float* conv_b    = (const float*)d_in[5];
  const float* x_proj_w  = (const float*)d_in[6];
  const float* dt_projs_w= (const float*)d_in[7];
  const float* dt_projs_b= (const float*)d_in[8];
  const float* A_logs    = (const float*)d_in[9];
  const float* Ds        = (const float*)d_in[10];
  const float* out_norm_w= (const float*)d_in[11];
  const float* out_norm_b= (const float*)d_in[12];
  const float* out_proj_w= (const float*)d_in[13];
  float* out = (float*)d_out;

  // workspace layout (liveness-packed, total 187,695,104 B < proven 192,937,984 B)
  char* ws = (char*)d_ws;
  float* z              = (float*)(ws);                         // 33.55 MB [GEMM1..merge]
  float* xc             = (float*)(ws + 33554432ULL);           // 33.55 MB [conv..passB]
  float* xpart          = (float*)(ws + 67108864ULL);           // 33.55 MB [GEMM1..conv]
  float* st             = xpart;                                //          [passA..passB]
  __hip_bfloat16* ymb   = (__hip_bfloat16*)xpart;               // 16.8 MB  [merge..GEMM2]
  float* xdbl           = (float*)(ws + 100663296ULL);          //  8.39 MB [xdbl..passB]
  __hip_bfloat16* ys    = (__hip_bfloat16*)(ws + 109051904ULL); // 67.11 MB [passB..merge]
  __hip_bfloat16* xnb   = (__hip_bfloat16*)(ws + 176160768ULL); //  8.39 MB [ln..GEMM1]
  __hip_bfloat16* w1b   = (__hip_bfloat16*)(ws + 184549376ULL); //  2.10 MB [cast..GEMM1]
  __hip_bfloat16* w2b   = (__hip_bfloat16*)(ws + 186646528ULL); //  1.05 MB [cast..GEMM2]

  // 0) weight casts
  cast_bf16_kernel<<<1024, 256, 0, stream>>>(in_proj_w, w1b, (2048 * 512) / 4);
  cast_bf16_kernel<<<512, 256, 0, stream>>>(out_proj_w, w2b, (512 * 1024) / 4);
  // 1) LayerNorm (bf16 out)
  ln_kernel<<<M_, 256, 0, stream>>>(x, norm_w, norm_b, xnb);
  // 2) xz = xn @ in_proj_w.T  (MFMA) -> split xpart | z (f32)
  gemm_bf16<0><<<dim3(2048 / 128, M_ / 128), 256, 0, stream>>>(
      xnb, w1b, M_, 2048, C_, xpart, z, nullptr);
  // 3) depthwise conv + SiLU
  conv_silu_kernel<<<M_, 256, 0, stream>>>(xpart, conv_w, conv_b, xc);
  // 4) x_dbl projections
  xdbl_kernel<<<B_ * K_ * 64, 256, 0, stream>>>(xc, x_proj_w, xdbl);
  // 5) chunked parallel selective scan
  scan_passA<<<B_ * K_ * 16 * NC_, 64, 0, stream>>>(
      xc, xdbl, dt_projs_w, dt_projs_b, A_logs, st);
  scan_mid<<<(B_ * K_ * DI_) / 256, 256, 0, stream>>>(st);
  scan_passB<<<B_ * K_ * 16 * NC_, 64, 0, stream>>>(
      xc, xdbl, dt_projs_w, dt_projs_b, A_logs, Ds, st, ys);
  // 6) merge + out-LN + SiLU(z) gate (bf16 out)
  merge_kernel<<<M_, 256, 0, stream>>>(ys, z, out_norm_w, out_norm_b, ymb);
  // 7) out = ym @ out_proj_w.T + resid (MFMA)
  gemm_bf16<1><<<dim3(C_ / 128, M_ / 128), 256, 0, stream>>>(
      ymb, w2b, M_, C_, DI_, out, nullptr, x);
}